// Round 1
// baseline (78.131 us; speedup 1.0000x reference)
//
#include <hip/hip_runtime.h>

#define NB 4       // batch N
#define HH 24
#define WWD 24
#define TT 4
#define VV 32
#define MM 576     // H*W
#define NHEADS 4
#define LL 2

__device__ __forceinline__ float lrelu(float x) { return x > 0.f ? x : 0.2f * x; }
__device__ __forceinline__ float elu1(float x)  { return x > 0.f ? x : (expf(x) - 1.f); }

// ---------------------------------------------------------------------------
// Kernel 1: Wh[hd,n,v,m,t'] = sum_t x[n,m,t,v] * mw[hd,t,t'] + mb[hd,t']
// stored as Whv[((hd*4+n)*4+t')*MM + m]*VV + v   (v contiguous)
// one thread per (hd,n,m,v); each computes all 4 t' outputs (x reuse x4).
// ---------------------------------------------------------------------------
__global__ __launch_bounds__(256) void wh_kernel(const float* __restrict__ x,
                                                 const float* __restrict__ mw,
                                                 const float* __restrict__ mb,
                                                 float* __restrict__ Whv) {
    int idx = blockIdx.x * 256 + threadIdx.x;   // [0, 4*4*576*32)
    int v  = idx & 31;
    int r  = idx >> 5;          // [0, 9216)
    int m  = r % MM;
    int r2 = r / MM;            // [0,16)
    int n  = r2 & 3;
    int hd = r2 >> 2;

    const float* xp = x + ((size_t)(n * MM + m) * TT) * VV + v;
    float xv[4];
#pragma unroll
    for (int t = 0; t < 4; ++t) xv[t] = xp[t * VV];

    const float* w = mw + hd * 16;   // [t][t']
#pragma unroll
    for (int tp = 0; tp < 4; ++tp) {
        float o = mb[hd * 4 + tp];
#pragma unroll
        for (int t = 0; t < 4; ++t) o += xv[t] * w[t * 4 + tp];
        Whv[((size_t)((hd * 4 + n) * 4 + tp) * MM + m) * VV + v] = o;
    }
}

// ---------------------------------------------------------------------------
// Kernel 2: normalized adjacency per (layer, head). adj = B + I; min-max
// normalize; D^-1/2 adj D^-1/2. One block per (l*4+hd).
// ---------------------------------------------------------------------------
__global__ __launch_bounds__(256) void adj_kernel(const float* __restrict__ Bp,
                                                  float* __restrict__ adjn) {
    int b = blockIdx.x;
    const float* B = Bp + b * 1024;
    __shared__ float s_adj[1024];
    __shared__ float s_red[256];
    __shared__ float s_d12[32];
    __shared__ float s_min, s_max;
    int tid = threadIdx.x;

    float lmin = 1e30f, lmax = -1e30f;
    for (int p = tid; p < 1024; p += 256) {
        int i = p >> 5, j = p & 31;
        float val = B[p] + (i == j ? 1.f : 0.f);
        s_adj[p] = val;
        lmin = fminf(lmin, val);
        lmax = fmaxf(lmax, val);
    }
    s_red[tid] = lmin; __syncthreads();
    for (int s = 128; s > 0; s >>= 1) { if (tid < s) s_red[tid] = fminf(s_red[tid], s_red[tid + s]); __syncthreads(); }
    if (tid == 0) s_min = s_red[0];
    __syncthreads();
    s_red[tid] = lmax; __syncthreads();
    for (int s = 128; s > 0; s >>= 1) { if (tid < s) s_red[tid] = fmaxf(s_red[tid], s_red[tid + s]); __syncthreads(); }
    if (tid == 0) s_max = s_red[0];
    __syncthreads();

    float mn = s_min, inv = 1.f / (s_max - s_min);
    for (int p = tid; p < 1024; p += 256) s_adj[p] = (s_adj[p] - mn) * inv;
    __syncthreads();
    if (tid < 32) {
        float s = 0.f;
        for (int j = 0; j < 32; ++j) s += s_adj[tid * 32 + j];
        s_d12[tid] = rsqrtf(s);
    }
    __syncthreads();
    for (int p = tid; p < 1024; p += 256) {
        int i = p >> 5, j = p & 31;
        adjn[b * 1024 + p] = s_d12[i] * s_adj[p] * s_d12[j];
    }
}

// ---------------------------------------------------------------------------
// Kernel 3: per (hd,n): ei/ej reductions -> att softmax (LDS) ->
//           C[t][j][u] = sum_i att[t][i][j] * adjn[i][u]
// e separability: e[n,i,j,t] = ei[n,i,t] + ej[n,j,t] with
//   ei[v,t] = sum_{dh<6,w<24,tt<4} Wh[v, (6t+dh)*24+w, tt] * a[dh*192 + w*4 + tt]
//   ej: same with a[dh*192 + (w+24)*4 + tt]
// ---------------------------------------------------------------------------
__global__ __launch_bounds__(256) void attc_kernel(const float* __restrict__ Whv,
                                                   const float* __restrict__ a_l,
                                                   const float* __restrict__ adjn_l,
                                                   float* __restrict__ C) {
    int b = blockIdx.x;            // hd*4 + n
    int n = b & 3, hd = b >> 2;
    __shared__ float s_e[2][4][32];        // [which][t][v]
    __shared__ float s_att[4][32][32];     // [t][i][j]
    __shared__ float s_adj[1024];          // [i][u]
    int tid = threadIdx.x;

    for (int p = tid; p < 1024; p += 256) s_adj[p] = adjn_l[hd * 1024 + p];

    // stage A: ei/ej. thread -> (which, t, v)
    int which = tid >> 7;
    int t     = (tid >> 5) & 3;
    int v     = tid & 31;
    const float* Wb = Whv + (size_t)(hd * 4 + n) * 4 * MM * VV;
    const float* ap = a_l + hd * 1152 + which * 96;
    float acc = 0.f;
    for (int tt = 0; tt < 4; ++tt) {
        const float* Wt = Wb + (size_t)tt * MM * VV + v;
        const float* at = ap + tt;
        for (int dh = 0; dh < 6; ++dh) {
            int mbase = (6 * t + dh) * 24;
#pragma unroll
            for (int w = 0; w < 24; ++w)
                acc += Wt[(mbase + w) * VV] * at[dh * 192 + w * 4];
        }
    }
    s_e[which][t][v] = acc;
    __syncthreads();

    // stage B: att[t][i][j] = softmax_t( lrelu(ei[i,t] + ej[j,t]) )
    for (int p = tid; p < 1024; p += 256) {
        int i = p >> 5, j = p & 31;
        float e[4], mx = -1e30f;
#pragma unroll
        for (int q = 0; q < 4; ++q) {
            e[q] = lrelu(s_e[0][q][i] + s_e[1][q][j]);
            mx = fmaxf(mx, e[q]);
        }
        float s = 0.f;
#pragma unroll
        for (int q = 0; q < 4; ++q) { e[q] = expf(e[q] - mx); s += e[q]; }
        float invs = 1.f / s;
#pragma unroll
        for (int q = 0; q < 4; ++q) s_att[q][i][j] = e[q] * invs;
    }
    __syncthreads();

    // stage C: C[t][j][u]
    float* Cb = C + (size_t)(hd * 4 + n) * 4 * 1024;
    for (int p = tid; p < 1024; p += 256) {
        int j = p >> 5, u = p & 31;
        float c0 = 0.f, c1 = 0.f, c2 = 0.f, c3 = 0.f;
        for (int i = 0; i < 32; ++i) {
            float av = s_adj[i * 32 + u];
            c0 += s_att[0][i][j] * av;
            c1 += s_att[1][i][j] * av;
            c2 += s_att[2][i][j] * av;
            c3 += s_att[3][i][j] * av;
        }
        Cb[0 * 1024 + j * 32 + u] = c0;
        Cb[1 * 1024 + j * 32 + u] = c1;
        Cb[2 * 1024 + j * 32 + u] = c2;
        Cb[3 * 1024 + j * 32 + u] = c3;
    }
}

// ---------------------------------------------------------------------------
// Kernel 4: out[n,m,t,u] = 0.25 * sum_hd elu( sum_j Whv[hd,n,t,m,j] * C[hd,n,t,j,u] )
// block = (n, t, m-chunk of 8); 256 threads = 8 m x 32 u.
// ---------------------------------------------------------------------------
__global__ __launch_bounds__(256) void main_kernel(const float* __restrict__ Whv,
                                                   const float* __restrict__ C,
                                                   float* __restrict__ out) {
    int b = blockIdx.x;            // n*288 + t*72 + mc
    int mc = b % 72;
    int t  = (b / 72) & 3;
    int n  = b / 288;
    __shared__ float s_C[4][1024];     // [hd][j*32+u]
    __shared__ float s_W[4][8][32];    // [hd][dm][j]
    int tid = threadIdx.x;

    for (int p = tid; p < 4096; p += 256) {
        int hd = p >> 10, r = p & 1023;
        s_C[hd][r] = C[(size_t)((hd * 4 + n) * 4 + t) * 1024 + r];
    }
    for (int p = tid; p < 1024; p += 256) {
        int hd = p >> 8, q = p & 255, dmm = q >> 5, j = q & 31;
        s_W[hd][dmm][j] = Whv[((size_t)((hd * 4 + n) * 4 + t) * MM + mc * 8 + dmm) * VV + j];
    }
    __syncthreads();

    int dm = tid >> 5, u = tid & 31;
    int m = mc * 8 + dm;
    float acc = 0.f;
#pragma unroll
    for (int hd = 0; hd < 4; ++hd) {
        float s = 0.f;
#pragma unroll
        for (int j = 0; j < 32; ++j) s += s_W[hd][dm][j] * s_C[hd][j * 32 + u];
        acc += elu1(s);
    }
    out[((size_t)(n * MM + m) * TT + t) * VV + u] = 0.25f * acc;
}

// ---------------------------------------------------------------------------
extern "C" void kernel_launch(void* const* d_in, const int* in_sizes, int n_in,
                              void* d_out, int out_size, void* d_ws, size_t ws_size,
                              hipStream_t stream) {
    const float* x      = (const float*)d_in[0];
    const float* map_w  = (const float*)d_in[1];   // (2,4,4,4)
    const float* map_b  = (const float*)d_in[2];   // (2,4,4)
    const float* a_temp = (const float*)d_in[3];   // (2,4,1152)
    const float* Bp     = (const float*)d_in[4];   // (2,4,32,32)
    float* out = (float*)d_out;
    float* ws  = (float*)d_ws;

    float* Whv   = ws;                  // 1,179,648 floats
    float* adjn  = Whv + 1179648;       //     8,192
    float* Cbuf  = adjn + 8192;         //    65,536
    float* inter = Cbuf + 65536;        //   294,912   (total ~6.2 MB)

    adj_kernel<<<8, 256, 0, stream>>>(Bp, adjn);
    for (int l = 0; l < 2; ++l) {
        const float* xin = (l == 0) ? x : inter;
        float* xout      = (l == 1) ? out : inter;
        wh_kernel<<<1152, 256, 0, stream>>>(xin, map_w + l * 64, map_b + l * 16, Whv);
        attc_kernel<<<16, 256, 0, stream>>>(Whv, a_temp + l * NHEADS * 1152,
                                            adjn + l * NHEADS * 1024, Cbuf);
        main_kernel<<<1152, 256, 0, stream>>>(Whv, Cbuf, xout);
    }
}